// Round 14
// baseline (43.567 us; speedup 1.0000x reference)
//
#include <hip/hip_runtime.h>

#define S_DIM 4096
#define B_DIM 8
#define LN_EPS 1e-3f

typedef _Float16 half8 __attribute__((ext_vector_type(8)));
typedef float f32x4 __attribute__((ext_vector_type(4)));

// ---------------------------------------------------------------------------
// Dispatch 1: blocks 0..1023 = prep (wt3), 1024..1535 = banded stage1.
// wt3 layout (element idx): ((a*4 + ks)*2 + ch)*512 + l*8 + e  holds
//   W[k][a][c] with k = ks*16 + (l&15), c = ch*32 + (l>>4)*8 + e.
// -> per (a, ks, ch) fragment is 1KB contiguous, lane l <-> bytes l*16,
//    matching the MFMA B-operand convention (k=lr, c=lg*8+e) exactly.
// ---------------------------------------------------------------------------
__global__ __launch_bounds__(256) void prep_stage1(const float* __restrict__ x,
                                                   const float* __restrict__ W,
                                                   _Float16* __restrict__ wt3,
                                                   _Float16* __restrict__ s_out) {
    if (blockIdx.x < 1024) {   // ---- prep role ----
        int idx = blockIdx.x * 256 + threadIdx.x;
        int e  = idx & 7;
        int l2 = (idx >> 3) & 63;
        int ch = (idx >> 9) & 1;
        int ks = (idx >> 10) & 3;
        int a  = idx >> 12;
        int k = ks * 16 + (l2 & 15);
        int c = ch * 32 + ((l2 >> 4) << 3) + e;
        wt3[idx] = (_Float16)W[((k << 6) + a) * 64 + c];
        return;
    }
    // ---- stage1 role: banded s_pre (d <= 128..192), known-good ----
    const int lin = blockIdx.x - 1024;
    const int it = lin & 63;
    const int by = lin >> 6;
    const int i0 = it * 64;
    const int tid = threadIdx.x;
    const int w = tid >> 6, l = tid & 63, lg = l >> 4, lr = l & 15;

    __shared__ _Float16 Bs[64 * 72];

    f32x4 acc[4] = {};
    const float iRowF = (float)(i0 + w * 16 + lr);
    const int ldC = tid & 63;
    const int ldJ = (tid >> 6) * 16;

    const int jt0 = (it >= 2) ? (it - 2) : 0;
    for (int jt = jt0; jt <= it; ++jt) {
        const int j0 = jt * 64;
        __syncthreads();
        {
            const float* xp = x + ((size_t)by * S_DIM + j0 + ldJ) * 64 + ldC;
            half8 v0, v1;
            #pragma unroll
            for (int q = 0; q < 8; ++q) {
                v0[q] = (_Float16)xp[q * 64];
                v1[q] = (_Float16)xp[(8 + q) * 64];
            }
            *(half8*)&Bs[ldC * 72 + ldJ] = v0;
            *(half8*)&Bs[ldC * 72 + ldJ + 8] = v1;
        }
        __syncthreads();
        #pragma unroll
        for (int kk = 0; kk < 2; ++kk) {
            half8 af;
            #pragma unroll
            for (int bq = 0; bq < 8; ++bq) {
                int j = j0 + kk * 32 + lg * 8 + bq;
                float df = iRowF - (float)j;
                float tv = (df > 0.f) ? __builtin_amdgcn_rcpf(df * df) : 0.f;
                af[bq] = (_Float16)tv;
            }
            #pragma unroll
            for (int nt = 0; nt < 4; ++nt) {
                half8 bf = *(const half8*)&Bs[(nt * 16 + lr) * 72 + kk * 32 + lg * 8];
                acc[nt] = __builtin_amdgcn_mfma_f32_16x16x32_f16(af, bf, acc[nt], 0, 0, 0);
            }
        }
    }

    #pragma unroll
    for (int nt = 0; nt < 4; ++nt)
        #pragma unroll
        for (int r = 0; r < 4; ++r)
            s_out[((size_t)by * S_DIM + i0 + w * 16 + lg * 4 + r) * 64 + nt * 16 + lr]
                = (_Float16)acc[nt][r];
}

// ---------------------------------------------------------------------------
// Stage 2 v12: N-SPLIT x A-SPLIT, minimal W traffic.
//   256 blocks (1/CU) x 128 rows, 512 thr = 8 waves = 4 ks (16 cols) x 2 ah
//   (a-half). Each wave owns a DISTINCT 64KB W slice -> 512 KB/CU total,
//   read once. rt=8 row-tiles/wave, acc=32 VGPR, sf=64, W ping-pong regs.
//   Barrier-free K-loop (compiler-managed vmcnt, v8 skeleton). xa from LDS.
//   Epilogue: f16 ah-combine (16KB) + per-row sum/ssq exchange + LN.
// ---------------------------------------------------------------------------
__global__ __launch_bounds__(512) void stage2(const float* __restrict__ x,
                                              const _Float16* __restrict__ s,
                                              const _Float16* __restrict__ wt3,
                                              const float* __restrict__ gamma,
                                              const float* __restrict__ beta,
                                              float* __restrict__ out) {
    const int r0 = blockIdx.x * 128;
    const int tid = threadIdx.x;
    const int w = tid >> 6, l = tid & 63, lg = l >> 4, lr = l & 15;
    const int ks = w & 3;          // col group: cols [ks*16, +16)
    const int ah = w >> 2;         // a half:    a in [ah*32, +32)

    __shared__ __align__(16) _Float16 xT[128 * 72];        // 18 KB xa table
    __shared__ __align__(16) _Float16 Pf[4][128 * 18];     // 18 KB ah-combine
    __shared__ float Sm[4][130];                           // per-ks row sums
    __shared__ float Sq[4][130];

    // ---- prologue: sf to regs, x -> xT (f16) ----
    half8 sf[8][2];
    #pragma unroll
    for (int rt = 0; rt < 8; ++rt) {
        const size_t row = (size_t)(r0 + rt * 16 + lr) * 64;
        sf[rt][0] = *(const half8*)&s[row + lg * 8];
        sf[rt][1] = *(const half8*)&s[row + 32 + lg * 8];
    }
    {
        const int row = tid >> 2, c0 = (tid & 3) * 16;
        const float* xp = x + (size_t)(r0 + row) * 64 + c0;
        #pragma unroll
        for (int hh = 0; hh < 2; ++hh) {
            float4 v0 = *(const float4*)(xp + hh * 8);
            float4 v1 = *(const float4*)(xp + hh * 8 + 4);
            half8 hv;
            hv[0] = (_Float16)v0.x; hv[1] = (_Float16)v0.y;
            hv[2] = (_Float16)v0.z; hv[3] = (_Float16)v0.w;
            hv[4] = (_Float16)v1.x; hv[5] = (_Float16)v1.y;
            hv[6] = (_Float16)v1.z; hv[7] = (_Float16)v1.w;
            *(half8*)&xT[row * 72 + c0 + hh * 8] = hv;
        }
    }
    __syncthreads();

    // this wave's W stream: a = ah*32 + t, frags (ks, ch) of 1KB
    const char* mylane = (const char*)wt3 + (size_t)ks * 2048 + l * 16;
    const size_t aBase = (size_t)ah * 32;

    half8 WA[2], WB[2];
#define PREF(BUF, t_)                                                          \
    {                                                                          \
        const char* p_ = mylane + (aBase + (t_)) * 8192;                       \
        BUF[0] = *(const half8*)(p_);                                          \
        BUF[1] = *(const half8*)(p_ + 1024);                                   \
    }

    f32x4 acc[8] = {};
#define CLUSTER(BUF, t_)                                                       \
    {                                                                          \
        __builtin_amdgcn_s_setprio(1);                                         \
        _Pragma("unroll")                                                      \
        for (int rt_ = 0; rt_ < 8; ++rt_) {                                    \
            _Float16 xa = xT[(rt_ * 16 + lr) * 72 + ah * 32 + (t_)];           \
            half8 af0 = sf[rt_][0] * xa;                                       \
            half8 af1 = sf[rt_][1] * xa;                                       \
            acc[rt_] = __builtin_amdgcn_mfma_f32_16x16x32_f16(                 \
                af0, BUF[0], acc[rt_], 0, 0, 0);                               \
            acc[rt_] = __builtin_amdgcn_mfma_f32_16x16x32_f16(                 \
                af1, BUF[1], acc[rt_], 0, 0, 0);                               \
        }                                                                      \
        __builtin_amdgcn_s_setprio(0);                                         \
    }

    PREF(WA, 0);
    #pragma unroll
    for (int tt = 0; tt < 16; ++tt) {
        const int t0 = tt * 2;
        PREF(WB, t0 + 1);                    // in flight during cluster t0
        CLUSTER(WA, t0);
        if (t0 + 2 < 32) PREF(WA, t0 + 2);   // in flight during cluster t0+1
        CLUSTER(WB, t0 + 1);
    }
#undef PREF
#undef CLUSTER

    // ---- epilogue ----
    // (1) ah=1 dumps f16 partials; ah=0 combines.
    if (ah == 1) {
        #pragma unroll
        for (int rt = 0; rt < 8; ++rt)
            #pragma unroll
            for (int reg = 0; reg < 4; ++reg)
                Pf[ks][(rt * 16 + lg * 4 + reg) * 18 + lr] = (_Float16)acc[rt][reg];
    }
    __syncthreads();

    if (ah == 0) {
        // (2) combine + residual; per-row 16-col partial sums -> LDS
        #pragma unroll
        for (int rt = 0; rt < 8; ++rt) {
            #pragma unroll
            for (int reg = 0; reg < 4; ++reg) {
                const int row = rt * 16 + lg * 4 + reg;
                float v = acc[rt][reg]
                        + (float)Pf[ks][row * 18 + lr]
                        + x[(size_t)(r0 + row) * 64 + ks * 16 + lr];
                acc[rt][reg] = v;                     // keep for normalize
                float s_ = v, q_ = v * v;
                s_ += __shfl_xor(s_, 1, 64);  q_ += __shfl_xor(q_, 1, 64);
                s_ += __shfl_xor(s_, 2, 64);  q_ += __shfl_xor(q_, 2, 64);
                s_ += __shfl_xor(s_, 4, 64);  q_ += __shfl_xor(q_, 4, 64);
                s_ += __shfl_xor(s_, 8, 64);  q_ += __shfl_xor(q_, 8, 64);
                if (lr == 0) {
                    Sm[ks][row] = s_;
                    Sq[ks][row] = q_;
                }
            }
        }
    }
    __syncthreads();

    if (ah == 0) {
        // (3) global mean/var per row, normalize, store own 16 cols
        const float gba = gamma[ks * 16 + lr];
        const float bta = beta[ks * 16 + lr];
        #pragma unroll
        for (int rt = 0; rt < 8; ++rt) {
            #pragma unroll
            for (int reg = 0; reg < 4; ++reg) {
                const int row = rt * 16 + lg * 4 + reg;
                const float sum = Sm[0][row] + Sm[1][row] + Sm[2][row] + Sm[3][row];
                const float ssq = Sq[0][row] + Sq[1][row] + Sq[2][row] + Sq[3][row];
                const float mean = sum * (1.f / 64.f);
                const float var = ssq * (1.f / 64.f) - mean * mean;
                const float rstd = __frsqrt_rn(var + LN_EPS);
                const float y = (acc[rt][reg] - mean) * rstd * gba + bta;
                out[(size_t)(r0 + row) * 64 + ks * 16 + lr] = y;
            }
        }
    }
}

// ---------------------------------------------------------------------------
extern "C" void kernel_launch(void* const* d_in, const int* in_sizes, int n_in,
                              void* d_out, int out_size, void* d_ws, size_t ws_size,
                              hipStream_t stream) {
    const float* x     = (const float*)d_in[0];
    const float* W     = (const float*)d_in[1];
    const float* gamma = (const float*)d_in[2];
    const float* beta  = (const float*)d_in[3];
    float* outp        = (float*)d_out;

    char* ws = (char*)d_ws;
    _Float16* s_f16 = (_Float16*)ws;                                    // 4 MB
    _Float16* wt3   = (_Float16*)(ws + (size_t)B_DIM * S_DIM * 64 * 2); // 512 KB

    prep_stage1<<<1536, 256, 0, stream>>>(x, W, wt3, s_f16);
    stage2<<<(B_DIM * S_DIM) / 128, 512, 0, stream>>>(x, s_f16, wt3, gamma, beta, outp);
}